// Round 1
// baseline (748.951 us; speedup 1.0000x reference)
//
#include <hip/hip_runtime.h>

// VecInt (scaling-and-squaring integration) for vel field (2,160,192,160,3) fp32.
// disp = vel / 2^7; repeat 7x: disp = disp + trilinear_sample(disp, grid + disp).
// Ping-pong between d_ws (buffer A, 118MB) and d_out; 7 (odd) steps starting
// from d_ws ends with the final result in d_out.

namespace {

constexpr int Dd = 160, Hh = 192, Ww = 160, Bb = 2;
constexpr int HW  = Hh * Ww;                 // 30720
constexpr int VOX = Dd * Hh * Ww;            // 4,915,200 per batch
constexpr int NTOT = Bb * VOX;               // 9,830,400 voxels
constexpr long long NFLT = (long long)NTOT * 3;  // 29,491,200 floats (div by 4)

__global__ __launch_bounds__(256) void scale_k(const float* __restrict__ in,
                                               float* __restrict__ out) {
    long long i = (long long)blockIdx.x * blockDim.x + threadIdx.x;
    const long long n4 = NFLT / 4;
    if (i < n4) {
        float4 v = reinterpret_cast<const float4*>(in)[i];
        constexpr float s = 1.0f / 128.0f;
        v.x *= s; v.y *= s; v.z *= s; v.w *= s;
        reinterpret_cast<float4*>(out)[i] = v;
    }
}

__global__ __launch_bounds__(256) void step_k(const float* __restrict__ disp,
                                              float* __restrict__ out) {
    int idx = blockIdx.x * blockDim.x + threadIdx.x;
    if (idx >= NTOT) return;

    // decompose idx -> (b, z, y, x); B=2 so batch split is a compare
    int b = (idx >= VOX) ? 1 : 0;
    int v = idx - b * VOX;
    int z = v / HW;
    int rem = v - z * HW;
    int y = rem / Ww;
    int x = rem - y * Ww;

    const float* __restrict__ vol = disp + (long long)b * VOX * 3;
    int base3 = idx * 3;  // < 29.5M, fits int
    float d0 = disp[base3 + 0];  // z-displacement (ij indexing: channel 0 = D axis)
    float d1 = disp[base3 + 1];  // y
    float d2 = disp[base3 + 2];  // x

    // sample location, clipped to volume extent
    float lz = fminf(fmaxf((float)z + d0, 0.0f), (float)(Dd - 1));
    float ly = fminf(fmaxf((float)y + d1, 0.0f), (float)(Hh - 1));
    float lx = fminf(fmaxf((float)x + d2, 0.0f), (float)(Ww - 1));

    float fz = floorf(lz), fy = floorf(ly), fx = floorf(lx);
    int z0 = (int)fz, y0 = (int)fy, x0 = (int)fx;
    int z1 = min(z0 + 1, Dd - 1);
    int y1 = min(y0 + 1, Hh - 1);
    int x1 = min(x0 + 1, Ww - 1);
    float tz = lz - fz, ty = ly - fy, tx = lx - fx;
    float sz = 1.0f - tz, sy = 1.0f - ty, sx = 1.0f - tx;

    float w000 = sz * sy * sx, w001 = sz * sy * tx;
    float w010 = sz * ty * sx, w011 = sz * ty * tx;
    float w100 = tz * sy * sx, w101 = tz * sy * tx;
    float w110 = tz * ty * sx, w111 = tz * ty * tx;

    int r00 = (z0 * Hh + y0) * Ww;
    int r01 = (z0 * Hh + y1) * Ww;
    int r10 = (z1 * Hh + y0) * Ww;
    int r11 = (z1 * Hh + y1) * Ww;

    const float* p000 = vol + (r00 + x0) * 3;
    const float* p001 = vol + (r00 + x1) * 3;
    const float* p010 = vol + (r01 + x0) * 3;
    const float* p011 = vol + (r01 + x1) * 3;
    const float* p100 = vol + (r10 + x0) * 3;
    const float* p101 = vol + (r10 + x1) * 3;
    const float* p110 = vol + (r11 + x0) * 3;
    const float* p111 = vol + (r11 + x1) * 3;

    float a0 = w000 * p000[0] + w001 * p001[0] + w010 * p010[0] + w011 * p011[0]
             + w100 * p100[0] + w101 * p101[0] + w110 * p110[0] + w111 * p111[0];
    float a1 = w000 * p000[1] + w001 * p001[1] + w010 * p010[1] + w011 * p011[1]
             + w100 * p100[1] + w101 * p101[1] + w110 * p110[1] + w111 * p111[1];
    float a2 = w000 * p000[2] + w001 * p001[2] + w010 * p010[2] + w011 * p011[2]
             + w100 * p100[2] + w101 * p101[2] + w110 * p110[2] + w111 * p111[2];

    out[base3 + 0] = d0 + a0;
    out[base3 + 1] = d1 + a1;
    out[base3 + 2] = d2 + a2;
}

}  // namespace

extern "C" void kernel_launch(void* const* d_in, const int* in_sizes, int n_in,
                              void* d_out, int out_size, void* d_ws, size_t ws_size,
                              hipStream_t stream) {
    const float* vel = (const float*)d_in[0];
    float* out = (float*)d_out;
    float* ws  = (float*)d_ws;   // needs NFLT*4 = ~118 MB

    // disp0 = vel / 128 -> ws
    {
        long long n4 = NFLT / 4;
        int blk = 256;
        int grd = (int)((n4 + blk - 1) / blk);
        scale_k<<<grd, blk, 0, stream>>>(vel, ws);
    }

    // 7 squaring steps, ping-pong ws <-> out; odd count ends in d_out.
    int blk = 256;
    int grd = (NTOT + blk - 1) / blk;
    float* a = ws;
    float* b = out;
    for (int it = 0; it < 7; ++it) {
        step_k<<<grd, blk, 0, stream>>>(a, b);
        float* t = a; a = b; b = t;
    }
}